// Round 18
// baseline (42.974 us; speedup 1.0000x reference)
//
#include <hip/hip_runtime.h>

#define NB 4
#define NN 2048
#define NF 256
#define NK 4
#define ND 64
#define NEG 0.2f
#define LOG2E 1.4426950408889634f

typedef _Float16 f16;
typedef _Float16 f16x2 __attribute__((ext_vector_type(2)));
typedef _Float16 f16x4 __attribute__((ext_vector_type(4)));
typedef _Float16 f16x8 __attribute__((ext_vector_type(8)));
typedef float f32x4 __attribute__((ext_vector_type(4)));
typedef float f32x16 __attribute__((ext_vector_type(16)));
typedef unsigned int u32;
typedef unsigned short u16;

// ---------------------------------------------------------------------------
// K01: unchanged (proven). k1 (blocks 0..255) + k0 (256..2303).
// k1: Wh^T per (b,k), f16, OCTET-MAJOR:
//     elem(d, j) at wht[(b*NK+k)*131072 + (j>>3)*512 + d*8 + (j&7)]
//   Epilogue: s -> sbuf(f32); t -> E=exp(t), F=exp(0.2t) as f16.
// k0: abit[b][i][jw] = bits of (adj>0 | I), 64 words/row.
// ---------------------------------------------------------------------------
__global__ __launch_bounds__(256) void k01(
    const float* __restrict__ x,      // (B,N,F)
    const int*   __restrict__ adj,    // (B,N,N)
    const float* __restrict__ Wm,     // (K,F,D)
    const float* __restrict__ a_src,  // (K,D)
    const float* __restrict__ a_dst,  // (K,D)
    unsigned int* __restrict__ abit,  // (B,N,64)
    f16* __restrict__ wht,            // octet-major
    float* __restrict__ sbuf,         // (B,K,N) f32
    f16* __restrict__ ebuf,           // (B,K,N) f16 exp(t)
    f16* __restrict__ fbuf)           // (B,K,N) f16 exp(0.2 t)
{
    __shared__ f16 wt[64 * 256];  // k1 only: W^T, xor-swizzled in f

    const int bx  = blockIdx.x;
    const int tid = threadIdx.x;

    if (bx >= 256) {
        // ---------------- k0: bit-pack ----------------
        const int row = (bx - 256) * 4 + (tid >> 6);  // b*NN + i
        const int l   = tid & 63;
        const int i   = row & (NN - 1);
        const int* __restrict__ ar = adj + (size_t)row * NN;

        int v[32];
#pragma unroll
        for (int c = 0; c < 32; ++c) v[c] = ar[c * 64 + l];

        unsigned int kx = 0, ky = 0;
#pragma unroll
        for (int c = 0; c < 32; ++c) {
            unsigned long long m = __ballot(v[c] > 0);
            if (l == c) { kx = (unsigned int)m; ky = (unsigned int)(m >> 32); }
        }
        if (l == (i >> 6)) {          // self-loop bit
            unsigned int sb = 1u << (i & 31);
            if (((i >> 5) & 1) == 0) kx |= sb; else ky |= sb;
        }
        if (l < 32) {
            uint2 kk; kk.x = kx; kk.y = ky;
            *(uint2*)&abit[(size_t)row * 64 + l * 2] = kk;
        }
        return;
    }

    // ---------------- k1: GEMM ----------------
    const int gx  = bx & 15;      // n-group of 128
    const int k   = (bx >> 4) & 3;
    const int b   = bx >> 6;
    const int wv  = tid >> 6;
    const int l   = tid & 63;
    const int q   = l >> 4;
    const int r16 = l & 15;

    for (int fc = 0; fc < 64; ++fc) {
        int f = fc * 4 + wv;
        int d = l;
        wt[d * 256 + (f ^ ((d & 7) << 3))] = (f16)Wm[(k * NF + f) * ND + d];
    }
    __syncthreads();

    const int ncol0 = gx * 128 + wv * 32;
    f32x4 acc[2][4];
#pragma unroll
    for (int nt = 0; nt < 2; ++nt)
#pragma unroll
        for (int dt = 0; dt < 4; ++dt)
            acc[nt][dt] = (f32x4){0.f, 0.f, 0.f, 0.f};

    for (int fs = 0; fs < 16; ++fs) {           // K-steps of 16
        const int f0 = fs * 16 + q * 4;
        f16x4 af[4];
#pragma unroll
        for (int dt = 0; dt < 4; ++dt) {
            int d = dt * 16 + r16;
            af[dt] = *(const f16x4*)&wt[d * 256 + (f0 ^ ((d & 7) << 3))];
        }
#pragma unroll
        for (int nt = 0; nt < 2; ++nt) {
            int n = ncol0 + nt * 16 + r16;
            float4 xv = *(const float4*)&x[((size_t)(b * NN + n)) * NF + f0];
            f16x4 bf = {(f16)xv.x, (f16)xv.y, (f16)xv.z, (f16)xv.w};
#pragma unroll
            for (int dt = 0; dt < 4; ++dt)
                acc[nt][dt] = __builtin_amdgcn_mfma_f32_16x16x16f16(
                    af[dt], bf, acc[nt][dt], 0, 0, 0);
        }
    }

    float asv[4][4], adv[4][4];
#pragma unroll
    for (int dt = 0; dt < 4; ++dt)
#pragma unroll
        for (int rr = 0; rr < 4; ++rr) {
            int d = dt * 16 + q * 4 + rr;
            asv[dt][rr] = a_src[k * ND + d];
            adv[dt][rr] = a_dst[k * ND + d];
        }

    const size_t obase = (size_t)(b * NK + k) * 131072;

#pragma unroll
    for (int nt = 0; nt < 2; ++nt) {
        int n  = ncol0 + nt * 16 + r16;
        const size_t sb_ = obase + (size_t)(n >> 3) * 512 + (n & 7);
        float sp = 0.f, tp = 0.f;
#pragma unroll
        for (int dt = 0; dt < 4; ++dt)
#pragma unroll
            for (int rr = 0; rr < 4; ++rr) {
                float v = acc[nt][dt][rr];
                int d = dt * 16 + q * 4 + rr;    // C row = d'
                wht[sb_ + d * 8] = (f16)v;
                sp += v * asv[dt][rr];
                tp += v * adv[dt][rr];
            }
        sp += __shfl_xor(sp, 16);
        sp += __shfl_xor(sp, 32);
        tp += __shfl_xor(tp, 16);
        tp += __shfl_xor(tp, 32);
        if (q == 0) {
            int idx = (b * NK + k) * NN + n;
            sbuf[idx] = sp;
            ebuf[idx] = (f16)__builtin_exp2f(tp * LOG2E);
            fbuf[idx] = (f16)__builtin_exp2f(0.2f * LOG2E * tp);
        }
    }
}

// ---------------------------------------------------------------------------
// K2 v17: v15's max-occupancy geometry + v16's atomic-free tree combine.
// Grid 1024 = 16 bkv (XCD-pinned: bid%8 const per bkv) x 64 row-groups of 32
// rows; block 512 = 8 waves = 8 j-chunks (256 j), sharing the 32 rows.
// LDS 18.4KB -> 4 blocks/CU -> 8 waves/SIMD (HW max; 2x v16) — the clean
// occupancy experiment (v15's null was CAS-atomic-poisoned, proven by v16's
// 102->41 recovery). Main loop = v15 verbatim (refcheck'd); combine = v16's
// TDUMP/TADD tree, 2-region sequential schedule; zero float atomics; no
// launch_bounds 2nd arg (v9/v13/v14: any explicit arg -> <=64-VGPR clamp).
// ---------------------------------------------------------------------------
__global__ __launch_bounds__(512) void k2_attn(
    const unsigned int* __restrict__ abit,  // (B,N,64) bit-mask
    const f16* __restrict__ wht,            // octet-major
    const float* __restrict__ sbuf,         // (B,K,N)
    const f16* __restrict__ ebuf,           // (B,K,N) f16
    const f16* __restrict__ fbuf,           // (B,K,N) f16
    float* __restrict__ out)                // (B,N,K*D)
{
    const int bid = blockIdx.x;
    const int bkv = bid & 15;            // XCD-pinned (b,k)
    const int rg  = bid >> 4;            // row-group 0..63
    const int b   = bkv >> 2, k = bkv & 3;
    const int i0  = rg * 32;
    const int tid = threadIdx.x;
    const int w   = tid >> 6;        // wave = j-chunk 0..7 (256 j each)
    const int l   = tid & 63;
    const int r32 = l & 31;
    const int hi  = l >> 5;
    const int iglob = i0 + r32;          // 32 rows; lanes l and l+32 same row

    // LDS: el @0 (4KB), fl @4096 (4KB) — overlaid by tree R0 @0..8K after
    // compute; R1 @8192..16384; dden @16384 (2KB). Total 18432B -> 4 blk/CU.
    __shared__ __attribute__((aligned(16))) char pool[18432];
    u16*   el      = (u16*)(pool);
    u16*   fl      = (u16*)(pool + 4096);
    float* ddenbuf = (float*)(pool + 16384);

    // adj bits: this lane's row, this wave's 256-j window (4 x uint2)
    const unsigned int* __restrict__ abrow =
        abit + (size_t)(b * NN + iglob) * 64 + w * 8;
    uint2 abx[4];
#pragma unroll
    for (int it = 0; it < 4; ++it) abx[it] = *(const uint2*)(abrow + it * 2);

    {   // stage E/F as f16 (4KB each), coalesced, once
        const u16* eb = (const u16*)(ebuf + bkv * NN);
        const u16* fb = (const u16*)(fbuf + bkv * NN);
        *(uint2*)&el[tid * 4] = *(const uint2*)&eb[tid * 4];
        *(uint2*)&fl[tid * 4] = *(const uint2*)&fb[tid * 4];
    }

    const float s  = sbuf[bkv * NN + iglob];
    const f16 Afh = (f16)__builtin_exp2f(0.8f * LOG2E * fminf(s, 0.f));   // <=1
    const f16 Bfh = (f16)__builtin_exp2f(-0.8f * LOG2E * fmaxf(s, 0.f));  // <=1
    const f16x2 Af2 = {Afh, Afh};
    const f16x2 Bf2 = {Bfh, Bfh};
    const f16x2 one2 = {(f16)1.0f, (f16)1.0f};

    // lane-constant fragment base: octet s = w*32 + it*8 + jts*2 + hi
    const f16* __restrict__ lanep =
        wht + (size_t)bkv * 131072 + (size_t)(w * 32 + hi) * 512 + r32 * 8;

    float den = 0.f;
    f32x16 acc[2];   // [0] = rows x d0-31, [1] = rows x d32-63
#pragma unroll
    for (int z = 0; z < 16; ++z) { acc[0][z] = 0.f; acc[1][z] = 0.f; }

    __syncthreads();   // el/fl visible

#pragma unroll
    for (int it = 0; it < 4; ++it) {          // 4 x 64 j = 256 j per wave
        const uint2 ab = abx[it];
#pragma unroll
        for (int jts = 0; jts < 4; ++jts) {
            const u32 word = (jts & 2) ? ab.y : ab.x;
            const u32 bbyte = (word >> (((jts & 1) << 4) + (hi << 3))) & 0xffu;
            const u32 u = (bbyte << 15) | bbyte;     // byte | byte<<15
            const int jb = w * 256 + it * 64 + jts * 16 + hi * 8;
            uint4 E4 = *(const uint4*)&el[jb];       // broadcast reads
            uint4 F4 = *(const uint4*)&fl[jb];
            u32 pa_u[4];
#pragma unroll
            for (int p = 0; p < 4; ++p) {
                f16x2 e2 = __builtin_bit_cast(f16x2, ((const u32*)&E4)[p]);
                f16x2 f2 = __builtin_bit_cast(f16x2, ((const u32*)&F4)[p]);
                f16x2 w2 = __builtin_elementwise_max(Af2 * e2, Bf2 * f2);
                u32 xx = (u >> (2 * p)) & 0x00010001u;   // {bit2p+1, bit2p}
                u32 mm = (xx << 16) - xx;                // FFFF/0000 halves
                pa_u[p] = __builtin_bit_cast(u32, w2) & mm;
                den = __builtin_amdgcn_fdot2(
                    __builtin_bit_cast(f16x2, pa_u[p]), one2, den, false);
            }
            uint4 pav = {pa_u[0], pa_u[1], pa_u[2], pa_u[3]};
            f16x8 pa = __builtin_bit_cast(f16x8, pav);

            // direct-global fragments: octet (w*32 + it*8 + jts*2 + hi)
            const f16* fp = lanep + (size_t)(it * 8 + jts * 2) * 512;
            f16x8 v80 = *(const f16x8*)(fp);         // d 0..31
            f16x8 v81 = *(const f16x8*)(fp + 256);   // d 32..63
            acc[0] = __builtin_amdgcn_mfma_f32_32x32x16_f16(pa, v80, acc[0], 0, 0, 0);
            acc[1] = __builtin_amdgcn_mfma_f32_32x32x16_f16(pa, v81, acc[1], 0, 0, 0);
        }
    }

    // per-wave row denominators -> non-atomic slots (wave-indexed)
    den += __shfl_xor(den, 32);
    if (hi == 0) ddenbuf[w * 32 + r32] = den;

    // ---- atomic-free tree over the 8 wave-partials (2 regions of 8KB) ----
#define TDUMP(reg)                                                             \
    do {                                                                       \
        float* rb = (float*)(pool + (reg) * 8192) + l * 32;                    \
        _Pragma("unroll") for (int dh = 0; dh < 2; ++dh)                       \
        _Pragma("unroll") for (int sub = 0; sub < 4; ++sub) {                  \
            f32x4 vv = {acc[dh][sub * 4], acc[dh][sub * 4 + 1],                \
                        acc[dh][sub * 4 + 2], acc[dh][sub * 4 + 3]};           \
            *(f32x4*)&rb[((dh * 4 + sub) ^ (l & 7)) << 2] = vv;                \
        }                                                                      \
    } while (0)
#define TADD(reg)                                                              \
    do {                                                                       \
        const float* rb = (const float*)(pool + (reg) * 8192) + l * 32;        \
        _Pragma("unroll") for (int dh = 0; dh < 2; ++dh)                       \
        _Pragma("unroll") for (int sub = 0; sub < 4; ++sub) {                  \
            f32x4 vv = *(const f32x4*)&rb[((dh * 4 + sub) ^ (l & 7)) << 2];    \
            _Pragma("unroll") for (int m = 0; m < 4; ++m)                      \
                acc[dh][sub * 4 + m] += vv[m];                                 \
        }                                                                      \
    } while (0)

    __syncthreads();
    if (w == 4) TDUMP(0); else if (w == 5) TDUMP(1);
    __syncthreads();
    if (w == 0) TADD(0); else if (w == 1) TADD(1);
    __syncthreads();
    if (w == 6) TDUMP(0); else if (w == 7) TDUMP(1);
    __syncthreads();
    if (w == 2) TADD(0); else if (w == 3) TADD(1);
    __syncthreads();
    if (w == 2) TDUMP(0); else if (w == 3) TDUMP(1);
    __syncthreads();
    if (w == 0) TADD(0); else if (w == 1) TADD(1);
    __syncthreads();
    if (w == 1) TDUMP(0);
    __syncthreads();
    if (w == 0) {
        TADD(0);
        float* dsum = (float*)(pool + 8192);   // R1 free now
        if (l < 32) {
            float dd = 0.f;
#pragma unroll
            for (int ww = 0; ww < 8; ++ww) dd += ddenbuf[ww * 32 + l];
            dsum[l] = 1.f / (dd + 1e-10f);
        }
        float* op = out + ((size_t)(b * NN) + i0) * (NK * ND) + k * ND;
#pragma unroll
        for (int dh = 0; dh < 2; ++dh)
#pragma unroll
            for (int rr = 0; rr < 16; ++rr) {
                const int row = (rr & 3) + 8 * (rr >> 2) + 4 * hi;  // C/D map
                op[(size_t)row * (NK * ND) + dh * 32 + r32] =
                    acc[dh][rr] * dsum[row];
            }
    }
#undef TDUMP
#undef TADD
}

extern "C" void kernel_launch(void* const* d_in, const int* in_sizes, int n_in,
                              void* d_out, int out_size, void* d_ws, size_t ws_size,
                              hipStream_t stream) {
    const float* x     = (const float*)d_in[0];
    const int*   adj   = (const int*)d_in[1];
    const float* Wm    = (const float*)d_in[2];
    const float* a_src = (const float*)d_in[3];
    const float* a_dst = (const float*)d_in[4];
    float* out = (float*)d_out;

    char* ws = (char*)d_ws;
    f16*   wht  = (f16*)ws;                                   // 4 MiB
    float* sbuf = (float*)(ws + (4u << 20));                  // 128 KiB
    f16*   ebuf = (f16*)(ws + (4u << 20) + (128u << 10));     // 64 KiB
    f16*   fbuf = (f16*)(ws + (4u << 20) + (192u << 10));     // 64 KiB
    unsigned int* abit = (unsigned int*)(ws + (4u << 20) + (256u << 10)); // 2 MiB

    k01<<<dim3(256 + NB * NN / 4), 256, 0, stream>>>(
        x, adj, Wm, a_src, a_dst, abit, wht, sbuf, ebuf, fbuf);
    k2_attn<<<dim3(1024), 512, 0, stream>>>(
        abit, wht, sbuf, ebuf, fbuf, out);
}

// Round 19
// 41.131 us; speedup vs baseline: 1.0448x; 1.0448x over previous
//
#include <hip/hip_runtime.h>

#define NB 4
#define NN 2048
#define NF 256
#define NK 4
#define ND 64
#define NEG 0.2f
#define LOG2E 1.4426950408889634f

typedef _Float16 f16;
typedef _Float16 f16x2 __attribute__((ext_vector_type(2)));
typedef _Float16 f16x4 __attribute__((ext_vector_type(4)));
typedef _Float16 f16x8 __attribute__((ext_vector_type(8)));
typedef float f32x4 __attribute__((ext_vector_type(4)));
typedef float f32x16 __attribute__((ext_vector_type(16)));
typedef unsigned int u32;
typedef unsigned short u16;

// ---------------------------------------------------------------------------
// K01: unchanged (proven). k1 (blocks 0..255) + k0 (256..2303).
// k1: Wh^T per (b,k), f16, OCTET-MAJOR:
//     elem(d, j) at wht[(b*NK+k)*131072 + (j>>3)*512 + d*8 + (j&7)]
//   Epilogue: s -> sbuf(f32); t -> E=exp(t), F=exp(0.2t) as f16.
// k0: abit[b][i][jw] = bits of (adj>0 | I), 64 words/row.
// ---------------------------------------------------------------------------
__global__ __launch_bounds__(256) void k01(
    const float* __restrict__ x,      // (B,N,F)
    const int*   __restrict__ adj,    // (B,N,N)
    const float* __restrict__ Wm,     // (K,F,D)
    const float* __restrict__ a_src,  // (K,D)
    const float* __restrict__ a_dst,  // (K,D)
    unsigned int* __restrict__ abit,  // (B,N,64)
    f16* __restrict__ wht,            // octet-major
    float* __restrict__ sbuf,         // (B,K,N) f32
    f16* __restrict__ ebuf,           // (B,K,N) f16 exp(t)
    f16* __restrict__ fbuf)           // (B,K,N) f16 exp(0.2 t)
{
    __shared__ f16 wt[64 * 256];  // k1 only: W^T, xor-swizzled in f

    const int bx  = blockIdx.x;
    const int tid = threadIdx.x;

    if (bx >= 256) {
        // ---------------- k0: bit-pack ----------------
        const int row = (bx - 256) * 4 + (tid >> 6);  // b*NN + i
        const int l   = tid & 63;
        const int i   = row & (NN - 1);
        const int* __restrict__ ar = adj + (size_t)row * NN;

        int v[32];
#pragma unroll
        for (int c = 0; c < 32; ++c) v[c] = ar[c * 64 + l];

        unsigned int kx = 0, ky = 0;
#pragma unroll
        for (int c = 0; c < 32; ++c) {
            unsigned long long m = __ballot(v[c] > 0);
            if (l == c) { kx = (unsigned int)m; ky = (unsigned int)(m >> 32); }
        }
        if (l == (i >> 6)) {          // self-loop bit
            unsigned int sb = 1u << (i & 31);
            if (((i >> 5) & 1) == 0) kx |= sb; else ky |= sb;
        }
        if (l < 32) {
            uint2 kk; kk.x = kx; kk.y = ky;
            *(uint2*)&abit[(size_t)row * 64 + l * 2] = kk;
        }
        return;
    }

    // ---------------- k1: GEMM ----------------
    const int gx  = bx & 15;      // n-group of 128
    const int k   = (bx >> 4) & 3;
    const int b   = bx >> 6;
    const int wv  = tid >> 6;
    const int l   = tid & 63;
    const int q   = l >> 4;
    const int r16 = l & 15;

    for (int fc = 0; fc < 64; ++fc) {
        int f = fc * 4 + wv;
        int d = l;
        wt[d * 256 + (f ^ ((d & 7) << 3))] = (f16)Wm[(k * NF + f) * ND + d];
    }
    __syncthreads();

    const int ncol0 = gx * 128 + wv * 32;
    f32x4 acc[2][4];
#pragma unroll
    for (int nt = 0; nt < 2; ++nt)
#pragma unroll
        for (int dt = 0; dt < 4; ++dt)
            acc[nt][dt] = (f32x4){0.f, 0.f, 0.f, 0.f};

    for (int fs = 0; fs < 16; ++fs) {           // K-steps of 16
        const int f0 = fs * 16 + q * 4;
        f16x4 af[4];
#pragma unroll
        for (int dt = 0; dt < 4; ++dt) {
            int d = dt * 16 + r16;
            af[dt] = *(const f16x4*)&wt[d * 256 + (f0 ^ ((d & 7) << 3))];
        }
#pragma unroll
        for (int nt = 0; nt < 2; ++nt) {
            int n = ncol0 + nt * 16 + r16;
            float4 xv = *(const float4*)&x[((size_t)(b * NN + n)) * NF + f0];
            f16x4 bf = {(f16)xv.x, (f16)xv.y, (f16)xv.z, (f16)xv.w};
#pragma unroll
            for (int dt = 0; dt < 4; ++dt)
                acc[nt][dt] = __builtin_amdgcn_mfma_f32_16x16x16f16(
                    af[dt], bf, acc[nt][dt], 0, 0, 0);
        }
    }

    float asv[4][4], adv[4][4];
#pragma unroll
    for (int dt = 0; dt < 4; ++dt)
#pragma unroll
        for (int rr = 0; rr < 4; ++rr) {
            int d = dt * 16 + q * 4 + rr;
            asv[dt][rr] = a_src[k * ND + d];
            adv[dt][rr] = a_dst[k * ND + d];
        }

    const size_t obase = (size_t)(b * NK + k) * 131072;

#pragma unroll
    for (int nt = 0; nt < 2; ++nt) {
        int n  = ncol0 + nt * 16 + r16;
        const size_t sb_ = obase + (size_t)(n >> 3) * 512 + (n & 7);
        float sp = 0.f, tp = 0.f;
#pragma unroll
        for (int dt = 0; dt < 4; ++dt)
#pragma unroll
            for (int rr = 0; rr < 4; ++rr) {
                float v = acc[nt][dt][rr];
                int d = dt * 16 + q * 4 + rr;    // C row = d'
                wht[sb_ + d * 8] = (f16)v;
                sp += v * asv[dt][rr];
                tp += v * adv[dt][rr];
            }
        sp += __shfl_xor(sp, 16);
        sp += __shfl_xor(sp, 32);
        tp += __shfl_xor(tp, 16);
        tp += __shfl_xor(tp, 32);
        if (q == 0) {
            int idx = (b * NK + k) * NN + n;
            sbuf[idx] = sp;
            ebuf[idx] = (f16)__builtin_exp2f(tp * LOG2E);
            fbuf[idx] = (f16)__builtin_exp2f(0.2f * LOG2E * tp);
        }
    }
}

// ---------------------------------------------------------------------------
// K2 v18: v16 (best known) + EXPLICIT PREFETCH RINGS in the main loop.
// Mechanism: compiler allocates only ~56-60 VGPRs (no clamp) -> cannot keep
// multiple fragment/E-F loads in flight -> exposed L2 (~250cy) and LDS
// (~120cy) latency each of 16 steps. Source-level software pipeline:
//   - global fragments: depth-2 ring (vf[3][2])
//   - LDS E/F: depth-1 ring (EF[2][2])
//   - all 8 adj words hoisted to prologue
// Loop fully unrolled -> all ring indices compile-time (rule #20).
// Geometry/combine identical to v16: 512 blocks, 8 waves x 256 j, 64 shared
// rows, acc[4], fdot2 denoms, atomic-free TDUMP/TADD tree, LDS 74KB.
// ---------------------------------------------------------------------------
__global__ __launch_bounds__(512) void k2_attn(
    const unsigned int* __restrict__ abit,  // (B,N,64) bit-mask
    const f16* __restrict__ wht,            // octet-major
    const float* __restrict__ sbuf,         // (B,K,N)
    const f16* __restrict__ ebuf,           // (B,K,N) f16
    const f16* __restrict__ fbuf,           // (B,K,N) f16
    float* __restrict__ out)                // (B,N,K*D)
{
    const int bid = blockIdx.x;
    const int bkv = (bid & 7) | (((bid >> 3) & 1) << 3);  // XCD-pinned (b,k)
    const int rg  = bid >> 4;                             // row-group 0..31
    const int b   = bkv >> 2, k = bkv & 3;
    const int i0  = rg * 64;
    const int tid = threadIdx.x;
    const int w   = tid >> 6;        // wave = j-chunk 0..7 (256 j each)
    const int l   = tid & 63;
    const int r32 = l & 31;
    const int hi  = l >> 5;
    const int row_a = i0 + r32;          // rowset a: i0..i0+31
    const int row_b = i0 + 32 + r32;     // rowset b: i0+32..i0+63

    // LDS: tree regions 4 x 16KB @0; el @65536 (4KB); fl @69632 (4KB);
    // ddenbuf @73728 (2KB). Total 75776B -> 2 blocks/CU.
    __shared__ __attribute__((aligned(16))) char pool[75776];
    u16*   el      = (u16*)(pool + 65536);
    u16*   fl      = (u16*)(pool + 69632);
    float* ddenbuf = (float*)(pool + 73728);

    {   // stage E/F as f16 (4KB each), coalesced, once
        const u16* eb = (const u16*)(ebuf + bkv * NN);
        const u16* fb = (const u16*)(fbuf + bkv * NN);
        *(uint2*)&el[tid * 4] = *(const uint2*)&eb[tid * 4];
        *(uint2*)&fl[tid * 4] = *(const uint2*)&fb[tid * 4];
    }

    const float s_a = sbuf[bkv * NN + row_a];
    const float s_b = sbuf[bkv * NN + row_b];
    const f16 Afa = (f16)__builtin_exp2f(0.8f * LOG2E * fminf(s_a, 0.f));
    const f16 Bfa = (f16)__builtin_exp2f(-0.8f * LOG2E * fmaxf(s_a, 0.f));
    const f16 Afb = (f16)__builtin_exp2f(0.8f * LOG2E * fminf(s_b, 0.f));
    const f16 Bfb = (f16)__builtin_exp2f(-0.8f * LOG2E * fmaxf(s_b, 0.f));
    const f16x2 Af2a = {Afa, Afa}, Bf2a = {Bfa, Bfa};
    const f16x2 Af2b = {Afb, Afb}, Bf2b = {Bfb, Bfb};
    const f16x2 one2 = {(f16)1.0f, (f16)1.0f};

    // hoist ALL adj words for this wave's 256-j window (prologue loads)
    const unsigned int* __restrict__ abrow_a =
        abit + (size_t)(b * NN + row_a) * 64 + w * 8;
    const unsigned int* __restrict__ abrow_b = abrow_a + 32 * 64;
    uint2 abx_a[4], abx_b[4];
#pragma unroll
    for (int it = 0; it < 4; ++it) {
        abx_a[it] = *(const uint2*)(abrow_a + it * 2);
        abx_b[it] = *(const uint2*)(abrow_b + it * 2);
    }

    // lane-constant fragment base: octet s = w*32 + it*8 + jts*2 + hi
    const f16* __restrict__ lanep =
        wht + (size_t)bkv * 131072 + (size_t)(w * 32 + hi) * 512 + r32 * 8;

    float den_a = 0.f, den_b = 0.f;
    f32x16 acc[4];   // [0]=a x d0-31, [1]=a x d32-63, [2]=b x d0-31, [3]=b x d32-63
#pragma unroll
    for (int t = 0; t < 4; ++t)
#pragma unroll
        for (int z = 0; z < 16; ++z) acc[t][z] = 0.f;

    __syncthreads();   // el/fl visible

#define PABUILD(PA, DEN, AF2, BF2, WORD)                                       \
    do {                                                                       \
        const u32 bbyte = ((WORD) >> (((jts & 1) << 4) + (hi << 3))) & 0xffu;  \
        const u32 u = (bbyte << 15) | bbyte;                                   \
        u32 pa_u[4];                                                           \
        _Pragma("unroll") for (int p = 0; p < 4; ++p) {                        \
            f16x2 e2 = __builtin_bit_cast(f16x2, ((const u32*)&E4)[p]);        \
            f16x2 f2 = __builtin_bit_cast(f16x2, ((const u32*)&F4)[p]);        \
            f16x2 w2 = __builtin_elementwise_max((AF2) * e2, (BF2) * f2);      \
            u32 xx = (u >> (2 * p)) & 0x00010001u;                             \
            u32 mm = (xx << 16) - xx;                                          \
            pa_u[p] = __builtin_bit_cast(u32, w2) & mm;                        \
            DEN = __builtin_amdgcn_fdot2(                                      \
                __builtin_bit_cast(f16x2, pa_u[p]), one2, DEN, false);         \
        }                                                                      \
        uint4 pav = {pa_u[0], pa_u[1], pa_u[2], pa_u[3]};                      \
        PA = __builtin_bit_cast(f16x8, pav);                                   \
    } while (0)

// step-addressing helpers (st = it*4 + jts, 16 steps of 16 j)
#define FRAG_ADDR(st) (lanep + (size_t)(((st) >> 2) * 8 + ((st) & 3) * 2) * 512)
#define JB(st) (w * 256 + ((st) >> 2) * 64 + ((st) & 3) * 16 + hi * 8)

    // prefetch rings: globals depth-2 (ring of 3), LDS depth-1 (ring of 2)
    f16x8 vf[3][2];
    uint4 EF[2][2];
    vf[0][0] = *(const f16x8*)(FRAG_ADDR(0));
    vf[0][1] = *(const f16x8*)(FRAG_ADDR(0) + 256);
    vf[1][0] = *(const f16x8*)(FRAG_ADDR(1));
    vf[1][1] = *(const f16x8*)(FRAG_ADDR(1) + 256);
    EF[0][0] = *(const uint4*)&el[JB(0)];
    EF[0][1] = *(const uint4*)&fl[JB(0)];

#pragma unroll
    for (int st = 0; st < 16; ++st) {
        const int it = st >> 2, jts = st & 3;
        // issue next loads first (independent of this step's compute)
        if (st < 14) {
            vf[(st + 2) % 3][0] = *(const f16x8*)(FRAG_ADDR(st + 2));
            vf[(st + 2) % 3][1] = *(const f16x8*)(FRAG_ADDR(st + 2) + 256);
        }
        if (st < 15) {
            EF[(st + 1) & 1][0] = *(const uint4*)&el[JB(st + 1)];
            EF[(st + 1) & 1][1] = *(const uint4*)&fl[JB(st + 1)];
        }
        const uint4 E4 = EF[st & 1][0];
        const uint4 F4 = EF[st & 1][1];
        const u32 word_a = (jts & 2) ? abx_a[it].y : abx_a[it].x;
        const u32 word_b = (jts & 2) ? abx_b[it].y : abx_b[it].x;
        f16x8 pa_a, pa_b;
        PABUILD(pa_a, den_a, Af2a, Bf2a, word_a);
        PABUILD(pa_b, den_b, Af2b, Bf2b, word_b);

        const f16x8 v80 = vf[st % 3][0];
        const f16x8 v81 = vf[st % 3][1];
        acc[0] = __builtin_amdgcn_mfma_f32_32x32x16_f16(pa_a, v80, acc[0], 0, 0, 0);
        acc[1] = __builtin_amdgcn_mfma_f32_32x32x16_f16(pa_a, v81, acc[1], 0, 0, 0);
        acc[2] = __builtin_amdgcn_mfma_f32_32x32x16_f16(pa_b, v80, acc[2], 0, 0, 0);
        acc[3] = __builtin_amdgcn_mfma_f32_32x32x16_f16(pa_b, v81, acc[3], 0, 0, 0);
    }
#undef PABUILD
#undef FRAG_ADDR
#undef JB

    // per-wave row denominators -> non-atomic slots (wave-indexed)
    den_a += __shfl_xor(den_a, 32);
    den_b += __shfl_xor(den_b, 32);
    if (hi == 0) {
        ddenbuf[w * 64 + r32]      = den_a;
        ddenbuf[w * 64 + 32 + r32] = den_b;
    }

    // ---- atomic-free 3-round tree over the 8 wave-partials ----
#define TDUMP(reg)                                                             \
    do {                                                                       \
        float* rb = (float*)(pool + (reg) * 16384) + l * 64;                   \
        _Pragma("unroll") for (int t = 0; t < 4; ++t)                          \
        _Pragma("unroll") for (int sub = 0; sub < 4; ++sub) {                  \
            f32x4 vv = {acc[t][sub * 4], acc[t][sub * 4 + 1],                  \
                        acc[t][sub * 4 + 2], acc[t][sub * 4 + 3]};             \
            *(f32x4*)&rb[((t * 4 + sub) ^ (l & 15)) << 2] = vv;                \
        }                                                                      \
    } while (0)
#define TADD(reg)                                                              \
    do {                                                                       \
        const float* rb = (const float*)(pool + (reg) * 16384) + l * 64;       \
        _Pragma("unroll") for (int t = 0; t < 4; ++t)                          \
        _Pragma("unroll") for (int sub = 0; sub < 4; ++sub) {                  \
            f32x4 vv = *(const f32x4*)&rb[((t * 4 + sub) ^ (l & 15)) << 2];    \
            _Pragma("unroll") for (int m = 0; m < 4; ++m)                      \
                acc[t][sub * 4 + m] += vv[m];                                  \
        }                                                                      \
    } while (0)

    __syncthreads();
    if (w >= 4) TDUMP(w - 4);
    __syncthreads();
    if (w < 4) TADD(w);
    if (w == 2 || w == 3) TDUMP(w);
    __syncthreads();
    if (w < 2) TADD(w + 2);
    if (w == 1) TDUMP(1);
    __syncthreads();
    if (w == 0) {
        TADD(1);
        // denominator sums (region 1 already consumed; reuse as dsum)
        float* dsum = (float*)(pool + 16384);
        float dd = 0.f;
#pragma unroll
        for (int ww = 0; ww < 8; ++ww) dd += ddenbuf[ww * 64 + l];
        dsum[l] = 1.f / (dd + 1e-10f);
        float* op = out + ((size_t)(b * NN) + i0) * (NK * ND) + k * ND;
#pragma unroll
        for (int t = 0; t < 4; ++t)
#pragma unroll
            for (int rr = 0; rr < 16; ++rr) {
                const int row = (t >> 1) * 32 + (rr & 3) + 8 * (rr >> 2) + 4 * hi;
                op[(size_t)row * (NK * ND) + (t & 1) * 32 + r32] =
                    acc[t][rr] * dsum[row];
            }
    }
#undef TDUMP
#undef TADD
}

extern "C" void kernel_launch(void* const* d_in, const int* in_sizes, int n_in,
                              void* d_out, int out_size, void* d_ws, size_t ws_size,
                              hipStream_t stream) {
    const float* x     = (const float*)d_in[0];
    const int*   adj   = (const int*)d_in[1];
    const float* Wm    = (const float*)d_in[2];
    const float* a_src = (const float*)d_in[3];
    const float* a_dst = (const float*)d_in[4];
    float* out = (float*)d_out;

    char* ws = (char*)d_ws;
    f16*   wht  = (f16*)ws;                                   // 4 MiB
    float* sbuf = (float*)(ws + (4u << 20));                  // 128 KiB
    f16*   ebuf = (f16*)(ws + (4u << 20) + (128u << 10));     // 64 KiB
    f16*   fbuf = (f16*)(ws + (4u << 20) + (192u << 10));     // 64 KiB
    unsigned int* abit = (unsigned int*)(ws + (4u << 20) + (256u << 10)); // 2 MiB

    k01<<<dim3(256 + NB * NN / 4), 256, 0, stream>>>(
        x, adj, Wm, a_src, a_dst, abit, wht, sbuf, ebuf, fbuf);
    k2_attn<<<dim3(512), 512, 0, stream>>>(
        abit, wht, sbuf, ebuf, fbuf, out);
}